// Round 15
// baseline (2064.624 us; speedup 1.0000x reference)
//
#include <hip/hip_runtime.h>
#include <cstdint>
#include <cstddef>

// NCA, 2 steps fused per launch. 32x32 output tile, 512 threads, grid 32x32 (natural
// row-major; R14's XCD swizzle REVERTED -- measured: it blew up FETCH 20.5->29MB,
// WRITE 33->50MB, L2 locality loss). State: NHWC f16, double-buffered. TWO barriers:
//   stage 36x36 halo-2 tileA -> B1
//   conv A over 34x34 domain (10 fixed groups/wave -- same makespan as guarded 73,
//   2-way unrolled for ILP; tail discarded by write guard) -> dxw(dx) ;
//   wave-local assemble: dxw <- x_{i+1}
//   B2
//   conv B over 32x32 (state = dxw, 34-wide) -> dx into tileA-as-scratch ;
//   wave-local update -> dst.
// Ring pixels recomputed bit-identically by neighbors -> no seams.
// Convs via mfma_f32_16x16x32_f16 (A=W1 permuted rows; then A=W2, B=h packed).
// gelu: tanh form x - x/(1+e^{2w}), 2w = x*(1.5957691+0.0713548 x^2), |err|~1.5e-4.
// PRNG: jax threefry2x32 partitionable: subkey[i]=raw pair tf2x32((0,42),(0,i));
// bits[p]=o0^o1 of tf2x32(subkey,(0,p)); mask = (bits>>9) > 2^22.

#define HH 1024
#define WW 1024
#define SD 8
#define TX 32
#define TY 32
#define DA 34            // domain-A width/height (34x34)
#define NA 1156          // 34*34
#define NGA 73           // ceil(1156/16)
#define SWA 36           // tileA row stride (pixels)

typedef _Float16 f16x8 __attribute__((ext_vector_type(8)));
typedef float f32x4 __attribute__((ext_vector_type(4)));
typedef uint32_t u32x2 __attribute__((ext_vector_type(2)));
typedef uint32_t u32x4 __attribute__((ext_vector_type(4)));

__host__ __device__ inline uint32_t rotl32(uint32_t x, int n) {
  return (x << n) | (x >> (32 - n));
}

__host__ __device__ inline void tf2x32(uint32_t k0, uint32_t k1,
                                       uint32_t x0, uint32_t x1,
                                       uint32_t& o0, uint32_t& o1) {
  uint32_t ks0 = k0, ks1 = k1, ks2 = k0 ^ k1 ^ 0x1BD11BDAu;
  x0 += ks0; x1 += ks1;
#define TFR(r) { x0 += x1; x1 = rotl32(x1, (r)); x1 ^= x0; }
  TFR(13) TFR(15) TFR(26) TFR(6)  x0 += ks1; x1 += ks2 + 1u;
  TFR(17) TFR(29) TFR(16) TFR(24) x0 += ks2; x1 += ks0 + 2u;
  TFR(13) TFR(15) TFR(26) TFR(6)  x0 += ks0; x1 += ks1 + 3u;
  TFR(17) TFR(29) TFR(16) TFR(24) x0 += ks1; x1 += ks2 + 4u;
  TFR(13) TFR(15) TFR(26) TFR(6)  x0 += ks2; x1 += ks0 + 5u;
#undef TFR
  o0 = x0; o1 = x1;
}

// gelu tanh-form: x - x/(1+e^{2w}), 2w = x*(1.5957691 + 0.0713548*x^2).
__device__ inline float gelu_fast(float x) {
  const float s = x * x;
  const float z = x * fmaf(0.0713548162f, s, 1.5957691216f);
  const float e = __expf(z);
  const float t = __builtin_amdgcn_rcpf(1.0f + e);
  return fmaf(-x, t, x);
}

// ---- bilinear upsample 8x8 -> 1024x1024, NHWC f16 out ----
__global__ void init_kernel(const float* __restrict__ seed, _Float16* __restrict__ dst) {
  int p = blockIdx.x * blockDim.x + threadIdx.x;
  if (p >= HH * WW) return;
  int y = p >> 10, x = p & 1023;
  float fy = (y + 0.5f) * (8.0f / HH) - 0.5f;
  float fx = (x + 0.5f) * (8.0f / WW) - 0.5f;
  int y0 = (int)floorf(fy); float wy = fy - (float)y0;
  int x0 = (int)floorf(fx); float wx = fx - (float)x0;
  int y0c = min(max(y0, 0), 7), y1c = min(max(y0 + 1, 0), 7);
  int x0c = min(max(x0, 0), 7), x1c = min(max(x0 + 1, 0), 7);
  f16x8 v;
#pragma unroll
  for (int c = 0; c < SD; ++c) {
    const float* s = seed + c * 64;
    float v00 = s[y0c * 8 + x0c], v01 = s[y0c * 8 + x1c];
    float v10 = s[y1c * 8 + x0c], v11 = s[y1c * 8 + x1c];
    float v0 = v00 + (v01 - v00) * wx;
    float v1 = v10 + (v11 - v10) * wx;
    v[c] = (_Float16)(v0 + (v1 - v0) * wy);
  }
  *(f16x8*)(dst + (size_t)p * 8) = v;
}

// ---- pack W1 (A-frags, PERMUTED rows) and W2 (A-frag, identity k-order) ----
__global__ void prep_kernel(const float* __restrict__ W1, const float* __restrict__ W2,
                            _Float16* __restrict__ w1f, _Float16* __restrict__ w2f) {
  int tid = threadIdx.x;
  for (int i = tid; i < 2 * 3 * 64; i += 256) {
    int nt = i / 192, rem = i % 192;
    int kc = rem / 64, lane = rem % 64;
    int ir = lane & 15;
    int ch = (ir >> 2) * 8 + (ir & 3) + nt * 4;   // permuted hidden channel
    int tap = kc * 4 + (lane >> 4);
#pragma unroll
    for (int j = 0; j < 8; ++j) {
      float v = (tap < 9) ? W1[(ch * SD + j) * 9 + tap] : 0.0f;
      w1f[i * 8 + j] = (_Float16)v;
    }
  }
  if (tid < 64) {
    int n = tid & 15, qk = tid >> 4;
#pragma unroll
    for (int j = 0; j < 8; ++j) {
      float v = (n < 8) ? W2[n * 32 + qk * 8 + j] : 0.0f;
      w2f[tid * 8 + j] = (_Float16)v;
    }
  }
}

// ---- fused double NCA step, 32x32 tile, 512 threads, 2 barriers, ILP-unrolled ----
__global__ __launch_bounds__(512, 8) void step2_kernel(
    const _Float16* __restrict__ src, _Float16* __restrict__ dst,
    const _Float16* __restrict__ w1f, const _Float16* __restrict__ w2f,
    const float* __restrict__ b1, const float* __restrict__ b2,
    uint32_t k0a, uint32_t k1a, uint32_t k0b, uint32_t k1b) {
  __shared__ _Float16 tileA[SWA * SWA * SD];  // 20736 B (state; later conv-B dx scratch)
  __shared__ _Float16 dxw[NA * SD];           // 18496 B (conv-A dx -> x_{i+1})

  const int tid = threadIdx.x;
  const int bx = blockIdx.x, by = blockIdx.y; // natural row-major grid (no swizzle)
  const int lane = tid & 63, w = tid >> 6;    // 8 waves
  const int m = lane & 15, q = lane >> 4;

  // ---- weight fragments + biases ----
  f16x8 af[2][3];
#pragma unroll
  for (int nt = 0; nt < 2; ++nt)
#pragma unroll
    for (int kc = 0; kc < 3; ++kc)
      af[nt][kc] = *(const f16x8*)(w1f + ((nt * 3 + kc) * 64 + lane) * 8);
  const f16x8 w2fr = *(const f16x8*)(w2f + lane * 8);
  const f32x4 b1q0 = *(const f32x4*)(b1 + q * 8);        // hidden chs q*8+{0..3}
  const f32x4 b1q1 = *(const f32x4*)(b1 + q * 8 + 4);    // hidden chs q*8+{4..7}
  const f32x4 b2q = *(const f32x4*)(b2 + (q & 1) * 4);   // out-chs q*4+{0..3} (q<2)

  // per-lane tap offsets for tileA (stride 36) and dxw-as-state (stride 34)
  int offA[3], offB[3];
#pragma unroll
  for (int kc = 0; kc < 3; ++kc) {
    int t = kc * 4 + q; if (t > 8) t = 0;     // taps 9..11: zero-weight rows, clamp addr
    offA[kc] = ((t / 3) * SWA + (t % 3)) * 8;
    offB[kc] = ((t / 3) * DA + (t % 3)) * 8;
  }

  // ---- stage halo-2 f16 tile (zero outside) ----
  for (int i = tid; i < SWA * SWA; i += 512) {
    int ly = i / SWA, lx = i - (i / SWA) * SWA;
    int gy = by * TY + ly - 2, gx = bx * TX + lx - 2;
    u32x4 v = {0u, 0u, 0u, 0u};
    if ((unsigned)gy < HH && (unsigned)gx < WW)
      v = *(const u32x4*)(src + (size_t)(gy * WW + gx) * 8);
    *(u32x4*)&tileA[i * 8] = v;
  }
  __syncthreads();                            // B1

  // ---- conv A: 10 fixed groups/wave, 2-way unrolled for ILP ----
  // (fixed trip = same makespan as guarded-73: wave 0 ran 10 groups either way.)
  // G in [73,79]: garbage (OOB LDS reads land inside the 39KB block alloc; writes
  // guarded by p<NA). (p*241)>>13 == p/34 exact for p < ~1300.
#pragma unroll 2
  for (int gi = 0; gi < 10; ++gi) {
    const int G = w + 8 * gi;                 // wave-uniform
    const int p = G * 16 + m;
    const int r = (p * 241) >> 13;
    const int c = p - r * DA;
    const int base = (r * SWA + c) * 8;
    f32x4 acc0 = b1q0, acc1 = b1q1;
#pragma unroll
    for (int kc = 0; kc < 3; ++kc) {
      const f16x8 bfrag = *(const f16x8*)&tileA[base + offA[kc]];
      acc0 = __builtin_amdgcn_mfma_f32_16x16x32_f16(af[0][kc], bfrag, acc0, 0, 0, 0);
      acc1 = __builtin_amdgcn_mfma_f32_16x16x32_f16(af[1][kc], bfrag, acc1, 0, 0, 0);
    }
    u32x4 a2d;
    {
      float g0 = gelu_fast(acc0[0]), g1 = gelu_fast(acc0[1]);
      float g2 = gelu_fast(acc0[2]), g3 = gelu_fast(acc0[3]);
      float g4 = gelu_fast(acc1[0]), g5 = gelu_fast(acc1[1]);
      float g6 = gelu_fast(acc1[2]), g7 = gelu_fast(acc1[3]);
      a2d[0] = __builtin_bit_cast(uint32_t, __builtin_amdgcn_cvt_pkrtz(g0, g1));
      a2d[1] = __builtin_bit_cast(uint32_t, __builtin_amdgcn_cvt_pkrtz(g2, g3));
      a2d[2] = __builtin_bit_cast(uint32_t, __builtin_amdgcn_cvt_pkrtz(g4, g5));
      a2d[3] = __builtin_bit_cast(uint32_t, __builtin_amdgcn_cvt_pkrtz(g6, g7));
    }
    const f16x8 hB = __builtin_bit_cast(f16x8, a2d);
    f32x4 acc2 = b2q;
    acc2 = __builtin_amdgcn_mfma_f32_16x16x32_f16(w2fr, hB, acc2, 0, 0, 0);
    if (q < 2 && p < NA) {
      u32x2 dd;
      dd[0] = __builtin_bit_cast(uint32_t, __builtin_amdgcn_cvt_pkrtz(acc2[0], acc2[1]));
      dd[1] = __builtin_bit_cast(uint32_t, __builtin_amdgcn_cvt_pkrtz(acc2[2], acc2[3]));
      *(u32x2*)&dxw[p * 8 + q * 4] = dd;
    }
  }

  // ---- wave-local assemble: dxw <- x_{i+1} = tileA(center) + dx*(0.1*maskA) ----
#pragma unroll
  for (int j = 0; j < 3; ++j) {
    const int G = w + 8 * (j * 4 + (lane >> 4));   // own groups
    const int p = G * 16 + m;
    if (G < NGA && p < NA) {
      const int r = (p * 241) >> 13;
      const int c = p - r * DA;
      const int gy = by * TY + r - 1, gx = bx * TX + c - 1;
      _Float16 mk = (_Float16)0.0f;
      if (((unsigned)gy < HH) && ((unsigned)gx < WW)) {
        uint32_t r0, r1;
        tf2x32(k0a, k1a, 0u, (uint32_t)(gy * WW + gx), r0, r1);
        mk = (((r0 ^ r1) >> 9) > 0x400000u) ? (_Float16)0.1f : (_Float16)0.0f;
      }
      const f16x8 xi = *(const f16x8*)&tileA[((r + 1) * SWA + (c + 1)) * 8];
      const f16x8 dx = *(const f16x8*)&dxw[p * 8];
      const f16x8 mk8 = {mk, mk, mk, mk, mk, mk, mk, mk};
      const f16x8 xo = dx * mk8 + xi;              // v_pk_fma_f16 x4 (OOB ring: 0+0=0)
      *(f16x8*)&dxw[p * 8] = xo;
    }
  }
  __syncthreads();                            // B2

  // ---- conv B: 8 groups/wave over 32x32 output, 2-way unrolled ----
#pragma unroll 2
  for (int gi = 0; gi < 8; ++gi) {
    const int G = w + 8 * gi;
    const int p = G * 16 + m;                 // output pixel 0..1023
    const int r = p >> 5, c = p & 31;
    const int base = (r * DA + c) * 8;
    f32x4 acc0 = b1q0, acc1 = b1q1;
#pragma unroll
    for (int kc = 0; kc < 3; ++kc) {
      const f16x8 bfrag = *(const f16x8*)&dxw[base + offB[kc]];
      acc0 = __builtin_amdgcn_mfma_f32_16x16x32_f16(af[0][kc], bfrag, acc0, 0, 0, 0);
      acc1 = __builtin_amdgcn_mfma_f32_16x16x32_f16(af[1][kc], bfrag, acc1, 0, 0, 0);
    }
    u32x4 a2d;
    {
      float g0 = gelu_fast(acc0[0]), g1 = gelu_fast(acc0[1]);
      float g2 = gelu_fast(acc0[2]), g3 = gelu_fast(acc0[3]);
      float g4 = gelu_fast(acc1[0]), g5 = gelu_fast(acc1[1]);
      float g6 = gelu_fast(acc1[2]), g7 = gelu_fast(acc1[3]);
      a2d[0] = __builtin_bit_cast(uint32_t, __builtin_amdgcn_cvt_pkrtz(g0, g1));
      a2d[1] = __builtin_bit_cast(uint32_t, __builtin_amdgcn_cvt_pkrtz(g2, g3));
      a2d[2] = __builtin_bit_cast(uint32_t, __builtin_amdgcn_cvt_pkrtz(g4, g5));
      a2d[3] = __builtin_bit_cast(uint32_t, __builtin_amdgcn_cvt_pkrtz(g6, g7));
    }
    const f16x8 hB = __builtin_bit_cast(f16x8, a2d);
    f32x4 acc2 = b2q;
    acc2 = __builtin_amdgcn_mfma_f32_16x16x32_f16(w2fr, hB, acc2, 0, 0, 0);
    if (q < 2) {
      u32x2 dd;
      dd[0] = __builtin_bit_cast(uint32_t, __builtin_amdgcn_cvt_pkrtz(acc2[0], acc2[1]));
      dd[1] = __builtin_bit_cast(uint32_t, __builtin_amdgcn_cvt_pkrtz(acc2[2], acc2[3]));
      *(u32x2*)&tileA[p * 8 + q * 4] = dd;    // tileA dead -> dx scratch
    }
  }

  // ---- wave-local update: dst = x_{i+1}(dxw, frozen since B2) + dx*(0.1*maskB) ----
#pragma unroll
  for (int j = 0; j < 2; ++j) {
    const int G = w + 8 * (j * 4 + (lane >> 4));   // own groups (all < 64)
    const int p = G * 16 + m;
    const int r = p >> 5, c = p & 31;
    const int pA = (r + 1) * DA + (c + 1);
    const uint32_t gp = (uint32_t)((by * TY + r) * WW + bx * TX + c);
    uint32_t r0, r1;
    tf2x32(k0b, k1b, 0u, gp, r0, r1);
    const _Float16 mk = (((r0 ^ r1) >> 9) > 0x400000u) ? (_Float16)0.1f : (_Float16)0.0f;
    const f16x8 xB = *(const f16x8*)&dxw[pA * 8];
    const f16x8 dx = *(const f16x8*)&tileA[p * 8];
    const f16x8 mk8 = {mk, mk, mk, mk, mk, mk, mk, mk};
    const f16x8 xo = dx * mk8 + xB;           // v_pk_fma_f16 x4
    *(f16x8*)(dst + (size_t)gp * 8) = xo;
  }
}

// ---- projection: out[p] = bp + sum_c x[p][c]*Wp[c] ----
__global__ void proj_kernel(const _Float16* __restrict__ x,
                            const float* __restrict__ Wp,
                            const float* __restrict__ bp,
                            float* __restrict__ out) {
  int p = blockIdx.x * blockDim.x + threadIdx.x;
  if (p >= HH * WW) return;
  const f16x8 xv = *(const f16x8*)(x + (size_t)p * 8);
  float acc = bp[0];
#pragma unroll
  for (int c = 0; c < SD; ++c) acc = fmaf((float)xv[c], Wp[c], acc);
  out[p] = acc;
}

extern "C" void kernel_launch(void* const* d_in, const int* in_sizes, int n_in,
                              void* d_out, int out_size, void* d_ws, size_t ws_size,
                              hipStream_t stream) {
  (void)in_sizes; (void)n_in; (void)out_size; (void)ws_size;
  const float* seed = (const float*)d_in[0];
  const float* W1   = (const float*)d_in[1];
  const float* b1   = (const float*)d_in[2];
  const float* W2   = (const float*)d_in[3];
  const float* b2   = (const float*)d_in[4];
  const float* Wp   = (const float*)d_in[5];
  const float* bp   = (const float*)d_in[6];
  float* out  = (float*)d_out;
  _Float16* buf0 = (_Float16*)d_ws;
  _Float16* buf1 = buf0 + (size_t)SD * HH * WW;
  _Float16* w1f  = buf1 + (size_t)SD * HH * WW;
  _Float16* w2f  = w1f + 2 * 3 * 64 * 8;

  // 64 subkeys of jax.random.split(jax.random.key(42), 64) (raw pairs, no xor)
  uint32_t ka[64], kb[64];
  for (int i = 0; i < 64; ++i) tf2x32(0u, 42u, 0u, (uint32_t)i, ka[i], kb[i]);

  hipLaunchKernelGGL(prep_kernel, dim3(1), dim3(256), 0, stream, W1, W2, w1f, w2f);
  hipLaunchKernelGGL(init_kernel, dim3((HH * WW) / 256), dim3(256), 0, stream, seed, buf0);

  dim3 grid(WW / TX, HH / TY);   // 32x32 = 1024 blocks = 4/CU, natural order
  _Float16* s = buf0; _Float16* d = buf1;
  for (int i = 0; i < 64; i += 2) {
    hipLaunchKernelGGL(step2_kernel, grid, dim3(512), 0, stream,
                       s, d, w1f, w2f, b1, b2, ka[i], kb[i], ka[i + 1], kb[i + 1]);
    _Float16* t = s; s = d; d = t;
  }
  hipLaunchKernelGGL(proj_kernel, dim3((HH * WW) / 256), dim3(256), 0, stream,
                     s, Wp, bp, out);
}

// Round 16
// 1344.071 us; speedup vs baseline: 1.5361x; 1.5361x over previous
//
#include <hip/hip_runtime.h>
#include <cstdint>
#include <cstddef>

// NCA, 2 steps fused per launch. 32x32 output tile, 512 threads, 1 tile-pair/block,
// grid 32x32 = 1024 blocks = exactly 4/CU. State: NHWC f16, double-buffered in d_ws.
// == Byte-exact revert to the R13 kernel (1336 us) ==
// R14/R15 isolated: the fixed-trip + #pragma unroll 2 ILP change caused scratch spills
// (VGPR pinned at 32 by the (512,8) budget) -> +12MB FETCH / +18MB WRITE of scratch
// traffic -> 2065 us. XCD swizzle (R14) was ALSO bad (+L2 misses). Both reverted.
// TWO barriers per block:
//   stage 36x36 halo-2 tileA -> B1
//   conv A over 34x34 domain -> dxw(dx) ; wave-local assemble: dxw <- x_{i+1}
//     (reads own dxw + tileA centers; tileA not modified; intra-wave ds order)
//   B2
//   conv B over 32x32 (reads dxw as state, 34-wide) -> dx into tileA-as-scratch ;
//   wave-local update: dst = tileA_scratch*0.1mask + dxw   (dxw frozen since B2)
// Ring pixels recomputed bit-identically by neighbor blocks -> no seams.
// Convs via mfma_f32_16x16x32_f16: A=W1 (rows permuted so lane(q,m) holds hidden chs
// q*8+{0..7} of pixel m after pkrtz pack = natural-k B-operand), then
// mfma(A=W2 identity-k, B=h) -> lane(q<2,m) = out-chs q*4+{0..3} of pixel m -> b64 write.
// gelu: tanh form x - x/(1+e^{2w}), 2w = x*(1.5957691+0.0713548 x^2), |err|~1.5e-4.
// PRNG: jax threefry2x32 partitionable: subkey[i]=raw pair tf2x32((0,42),(0,i));
// bits[p]=o0^o1 of tf2x32(subkey,(0,p)); mask = (bits>>9) > 2^22.

#define HH 1024
#define WW 1024
#define SD 8
#define TX 32
#define TY 32
#define DA 34            // domain-A width/height (34x34)
#define NA 1156          // 34*34
#define NGA 73           // ceil(1156/16)
#define SWA 36           // tileA row stride (pixels)

typedef _Float16 f16x8 __attribute__((ext_vector_type(8)));
typedef float f32x4 __attribute__((ext_vector_type(4)));
typedef uint32_t u32x2 __attribute__((ext_vector_type(2)));
typedef uint32_t u32x4 __attribute__((ext_vector_type(4)));

__host__ __device__ inline uint32_t rotl32(uint32_t x, int n) {
  return (x << n) | (x >> (32 - n));
}

__host__ __device__ inline void tf2x32(uint32_t k0, uint32_t k1,
                                       uint32_t x0, uint32_t x1,
                                       uint32_t& o0, uint32_t& o1) {
  uint32_t ks0 = k0, ks1 = k1, ks2 = k0 ^ k1 ^ 0x1BD11BDAu;
  x0 += ks0; x1 += ks1;
#define TFR(r) { x0 += x1; x1 = rotl32(x1, (r)); x1 ^= x0; }
  TFR(13) TFR(15) TFR(26) TFR(6)  x0 += ks1; x1 += ks2 + 1u;
  TFR(17) TFR(29) TFR(16) TFR(24) x0 += ks2; x1 += ks0 + 2u;
  TFR(13) TFR(15) TFR(26) TFR(6)  x0 += ks0; x1 += ks1 + 3u;
  TFR(17) TFR(29) TFR(16) TFR(24) x0 += ks1; x1 += ks2 + 4u;
  TFR(13) TFR(15) TFR(26) TFR(6)  x0 += ks2; x1 += ks0 + 5u;
#undef TFR
  o0 = x0; o1 = x1;
}

// gelu tanh-form: x - x/(1+e^{2w}), 2w = x*(1.5957691 + 0.0713548*x^2).
__device__ inline float gelu_fast(float x) {
  const float s = x * x;
  const float z = x * fmaf(0.0713548162f, s, 1.5957691216f);
  const float e = __expf(z);
  const float t = __builtin_amdgcn_rcpf(1.0f + e);
  return fmaf(-x, t, x);
}

// ---- bilinear upsample 8x8 -> 1024x1024, NHWC f16 out ----
__global__ void init_kernel(const float* __restrict__ seed, _Float16* __restrict__ dst) {
  int p = blockIdx.x * blockDim.x + threadIdx.x;
  if (p >= HH * WW) return;
  int y = p >> 10, x = p & 1023;
  float fy = (y + 0.5f) * (8.0f / HH) - 0.5f;
  float fx = (x + 0.5f) * (8.0f / WW) - 0.5f;
  int y0 = (int)floorf(fy); float wy = fy - (float)y0;
  int x0 = (int)floorf(fx); float wx = fx - (float)x0;
  int y0c = min(max(y0, 0), 7), y1c = min(max(y0 + 1, 0), 7);
  int x0c = min(max(x0, 0), 7), x1c = min(max(x0 + 1, 0), 7);
  f16x8 v;
#pragma unroll
  for (int c = 0; c < SD; ++c) {
    const float* s = seed + c * 64;
    float v00 = s[y0c * 8 + x0c], v01 = s[y0c * 8 + x1c];
    float v10 = s[y1c * 8 + x0c], v11 = s[y1c * 8 + x1c];
    float v0 = v00 + (v01 - v00) * wx;
    float v1 = v10 + (v11 - v10) * wx;
    v[c] = (_Float16)(v0 + (v1 - v0) * wy);
  }
  *(f16x8*)(dst + (size_t)p * 8) = v;
}

// ---- pack W1 (A-frags, PERMUTED rows) and W2 (A-frag, identity k-order) ----
__global__ void prep_kernel(const float* __restrict__ W1, const float* __restrict__ W2,
                            _Float16* __restrict__ w1f, _Float16* __restrict__ w2f) {
  int tid = threadIdx.x;
  for (int i = tid; i < 2 * 3 * 64; i += 256) {
    int nt = i / 192, rem = i % 192;
    int kc = rem / 64, lane = rem % 64;
    int ir = lane & 15;
    int ch = (ir >> 2) * 8 + (ir & 3) + nt * 4;   // permuted hidden channel
    int tap = kc * 4 + (lane >> 4);
#pragma unroll
    for (int j = 0; j < 8; ++j) {
      float v = (tap < 9) ? W1[(ch * SD + j) * 9 + tap] : 0.0f;
      w1f[i * 8 + j] = (_Float16)v;
    }
  }
  if (tid < 64) {
    int n = tid & 15, qk = tid >> 4;
#pragma unroll
    for (int j = 0; j < 8; ++j) {
      float v = (n < 8) ? W2[n * 32 + qk * 8 + j] : 0.0f;
      w2f[tid * 8 + j] = (_Float16)v;
    }
  }
}

// ---- fused double NCA step, 32x32 tile, 512 threads, 2 barriers ----
__global__ __launch_bounds__(512, 8) void step2_kernel(
    const _Float16* __restrict__ src, _Float16* __restrict__ dst,
    const _Float16* __restrict__ w1f, const _Float16* __restrict__ w2f,
    const float* __restrict__ b1, const float* __restrict__ b2,
    uint32_t k0a, uint32_t k1a, uint32_t k0b, uint32_t k1b) {
  __shared__ _Float16 tileA[SWA * SWA * SD];  // 20736 B (state; later conv-B dx scratch)
  __shared__ _Float16 dxw[NA * SD];           // 18496 B (conv-A dx -> x_{i+1})

  const int tid = threadIdx.x;
  const int bx = blockIdx.x, by = blockIdx.y;
  const int lane = tid & 63, w = tid >> 6;    // 8 waves
  const int m = lane & 15, q = lane >> 4;

  // ---- weight fragments + biases ----
  f16x8 af[2][3];
#pragma unroll
  for (int nt = 0; nt < 2; ++nt)
#pragma unroll
    for (int kc = 0; kc < 3; ++kc)
      af[nt][kc] = *(const f16x8*)(w1f + ((nt * 3 + kc) * 64 + lane) * 8);
  const f16x8 w2fr = *(const f16x8*)(w2f + lane * 8);
  const f32x4 b1q0 = *(const f32x4*)(b1 + q * 8);        // hidden chs q*8+{0..3}
  const f32x4 b1q1 = *(const f32x4*)(b1 + q * 8 + 4);    // hidden chs q*8+{4..7}
  const f32x4 b2q = *(const f32x4*)(b2 + (q & 1) * 4);   // out-chs q*4+{0..3} (q<2)

  // per-lane tap offsets for tileA (stride 36) and dxw-as-state (stride 34)
  int offA[3], offB[3];
#pragma unroll
  for (int kc = 0; kc < 3; ++kc) {
    int t = kc * 4 + q; if (t > 8) t = 0;     // taps 9..11: zero-weight rows, clamp addr
    offA[kc] = ((t / 3) * SWA + (t % 3)) * 8;
    offB[kc] = ((t / 3) * DA + (t % 3)) * 8;
  }

  // ---- stage halo-2 f16 tile: rows by*32-2.., cols bx*32-2.. (zero outside) ----
  for (int i = tid; i < SWA * SWA; i += 512) {
    int ly = i / SWA, lx = i - (i / SWA) * SWA;
    int gy = by * TY + ly - 2, gx = bx * TX + lx - 2;
    u32x4 v = {0u, 0u, 0u, 0u};
    if ((unsigned)gy < HH && (unsigned)gx < WW)
      v = *(const u32x4*)(src + (size_t)(gy * WW + gx) * 8);
    *(u32x4*)&tileA[i * 8] = v;
  }
  __syncthreads();                            // B1

  // ---- conv A over 34x34 domain -> dxw (dx), strided groups G = w + 8*gi ----
  for (int gi = 0; gi < 10; ++gi) {
    const int G = w + 8 * gi;                 // wave-uniform
    if (G >= NGA) break;
    const int p = G * 16 + m;                 // domain-A pixel (G=72: lanes m>=4 garbage,
    const int r = (p * 241) >> 13;            //  guarded below; OOB reads land in dxw, safe)
    const int c = p - r * DA;
    const int base = (r * SWA + c) * 8;
    f32x4 acc0 = b1q0, acc1 = b1q1;
#pragma unroll
    for (int kc = 0; kc < 3; ++kc) {
      const f16x8 bfrag = *(const f16x8*)&tileA[base + offA[kc]];
      acc0 = __builtin_amdgcn_mfma_f32_16x16x32_f16(af[0][kc], bfrag, acc0, 0, 0, 0);
      acc1 = __builtin_amdgcn_mfma_f32_16x16x32_f16(af[1][kc], bfrag, acc1, 0, 0, 0);
    }
    u32x4 a2d;
    {
      float g0 = gelu_fast(acc0[0]), g1 = gelu_fast(acc0[1]);
      float g2 = gelu_fast(acc0[2]), g3 = gelu_fast(acc0[3]);
      float g4 = gelu_fast(acc1[0]), g5 = gelu_fast(acc1[1]);
      float g6 = gelu_fast(acc1[2]), g7 = gelu_fast(acc1[3]);
      a2d[0] = __builtin_bit_cast(uint32_t, __builtin_amdgcn_cvt_pkrtz(g0, g1));
      a2d[1] = __builtin_bit_cast(uint32_t, __builtin_amdgcn_cvt_pkrtz(g2, g3));
      a2d[2] = __builtin_bit_cast(uint32_t, __builtin_amdgcn_cvt_pkrtz(g4, g5));
      a2d[3] = __builtin_bit_cast(uint32_t, __builtin_amdgcn_cvt_pkrtz(g6, g7));
    }
    const f16x8 hB = __builtin_bit_cast(f16x8, a2d);
    f32x4 acc2 = b2q;
    acc2 = __builtin_amdgcn_mfma_f32_16x16x32_f16(w2fr, hB, acc2, 0, 0, 0);
    if (q < 2 && p < NA) {
      u32x2 dd;
      dd[0] = __builtin_bit_cast(uint32_t, __builtin_amdgcn_cvt_pkrtz(acc2[0], acc2[1]));
      dd[1] = __builtin_bit_cast(uint32_t, __builtin_amdgcn_cvt_pkrtz(acc2[2], acc2[3]));
      *(u32x2*)&dxw[p * 8 + q * 4] = dd;
    }
  }

  // ---- wave-local assemble: dxw <- x_{i+1} = tileA(center) + dx*(0.1*maskA) ----
  // (transforms only this wave's own groups; tileA untouched; intra-wave ds order)
#pragma unroll
  for (int j = 0; j < 3; ++j) {
    const int G = w + 8 * (j * 4 + (lane >> 4));   // own groups, 4 per iter
    const int p = G * 16 + m;
    if (G < NGA && p < NA) {
      const int r = (p * 241) >> 13;
      const int c = p - r * DA;
      const int gy = by * TY + r - 1, gx = bx * TX + c - 1;
      _Float16 mk = (_Float16)0.0f;
      if (((unsigned)gy < HH) && ((unsigned)gx < WW)) {
        uint32_t r0, r1;
        tf2x32(k0a, k1a, 0u, (uint32_t)(gy * WW + gx), r0, r1);
        mk = (((r0 ^ r1) >> 9) > 0x400000u) ? (_Float16)0.1f : (_Float16)0.0f;
      }
      const f16x8 xi = *(const f16x8*)&tileA[((r + 1) * SWA + (c + 1)) * 8];
      const f16x8 dx = *(const f16x8*)&dxw[p * 8];
      const f16x8 mk8 = {mk, mk, mk, mk, mk, mk, mk, mk};
      const f16x8 xo = dx * mk8 + xi;              // v_pk_fma_f16 x4 (OOB ring: 0+0=0)
      *(f16x8*)&dxw[p * 8] = xo;
    }
  }
  __syncthreads();                            // B2

  // ---- conv B over 32x32 output (state = dxw, stride 34) -> dx into tileA scratch ----
  for (int gi = 0; gi < 8; ++gi) {
    const int G = w + 8 * gi;                 // 64 groups, 8 per wave
    const int p = G * 16 + m;                 // output pixel 0..1023
    const int r = p >> 5, c = p & 31;
    const int base = (r * DA + c) * 8;
    f32x4 acc0 = b1q0, acc1 = b1q1;
#pragma unroll
    for (int kc = 0; kc < 3; ++kc) {
      const f16x8 bfrag = *(const f16x8*)&dxw[base + offB[kc]];
      acc0 = __builtin_amdgcn_mfma_f32_16x16x32_f16(af[0][kc], bfrag, acc0, 0, 0, 0);
      acc1 = __builtin_amdgcn_mfma_f32_16x16x32_f16(af[1][kc], bfrag, acc1, 0, 0, 0);
    }
    u32x4 a2d;
    {
      float g0 = gelu_fast(acc0[0]), g1 = gelu_fast(acc0[1]);
      float g2 = gelu_fast(acc0[2]), g3 = gelu_fast(acc0[3]);
      float g4 = gelu_fast(acc1[0]), g5 = gelu_fast(acc1[1]);
      float g6 = gelu_fast(acc1[2]), g7 = gelu_fast(acc1[3]);
      a2d[0] = __builtin_bit_cast(uint32_t, __builtin_amdgcn_cvt_pkrtz(g0, g1));
      a2d[1] = __builtin_bit_cast(uint32_t, __builtin_amdgcn_cvt_pkrtz(g2, g3));
      a2d[2] = __builtin_bit_cast(uint32_t, __builtin_amdgcn_cvt_pkrtz(g4, g5));
      a2d[3] = __builtin_bit_cast(uint32_t, __builtin_amdgcn_cvt_pkrtz(g6, g7));
    }
    const f16x8 hB = __builtin_bit_cast(f16x8, a2d);
    f32x4 acc2 = b2q;
    acc2 = __builtin_amdgcn_mfma_f32_16x16x32_f16(w2fr, hB, acc2, 0, 0, 0);
    if (q < 2) {
      u32x2 dd;
      dd[0] = __builtin_bit_cast(uint32_t, __builtin_amdgcn_cvt_pkrtz(acc2[0], acc2[1]));
      dd[1] = __builtin_bit_cast(uint32_t, __builtin_amdgcn_cvt_pkrtz(acc2[2], acc2[3]));
      *(u32x2*)&tileA[p * 8 + q * 4] = dd;    // tileA dead -> dx scratch
    }
  }

  // ---- wave-local update: dst = x_{i+1}(dxw, frozen since B2) + dx*(0.1*maskB) ----
#pragma unroll
  for (int j = 0; j < 2; ++j) {
    const int G = w + 8 * (j * 4 + (lane >> 4));   // own groups, 4 per iter (all < 64)
    const int p = G * 16 + m;
    const int r = p >> 5, c = p & 31;
    const int pA = (r + 1) * DA + (c + 1);
    const uint32_t gp = (uint32_t)((by * TY + r) * WW + bx * TX + c);
    uint32_t r0, r1;
    tf2x32(k0b, k1b, 0u, gp, r0, r1);
    const _Float16 mk = (((r0 ^ r1) >> 9) > 0x400000u) ? (_Float16)0.1f : (_Float16)0.0f;
    const f16x8 xB = *(const f16x8*)&dxw[pA * 8];
    const f16x8 dx = *(const f16x8*)&tileA[p * 8];
    const f16x8 mk8 = {mk, mk, mk, mk, mk, mk, mk, mk};
    const f16x8 xo = dx * mk8 + xB;           // v_pk_fma_f16 x4
    *(f16x8*)(dst + (size_t)gp * 8) = xo;
  }
}

// ---- projection: out[p] = bp + sum_c x[p][c]*Wp[c] ----
__global__ void proj_kernel(const _Float16* __restrict__ x,
                            const float* __restrict__ Wp,
                            const float* __restrict__ bp,
                            float* __restrict__ out) {
  int p = blockIdx.x * blockDim.x + threadIdx.x;
  if (p >= HH * WW) return;
  const f16x8 xv = *(const f16x8*)(x + (size_t)p * 8);
  float acc = bp[0];
#pragma unroll
  for (int c = 0; c < SD; ++c) acc = fmaf((float)xv[c], Wp[c], acc);
  out[p] = acc;
}

extern "C" void kernel_launch(void* const* d_in, const int* in_sizes, int n_in,
                              void* d_out, int out_size, void* d_ws, size_t ws_size,
                              hipStream_t stream) {
  (void)in_sizes; (void)n_in; (void)out_size; (void)ws_size;
  const float* seed = (const float*)d_in[0];
  const float* W1   = (const float*)d_in[1];
  const float* b1   = (const float*)d_in[2];
  const float* W2   = (const float*)d_in[3];
  const float* b2   = (const float*)d_in[4];
  const float* Wp   = (const float*)d_in[5];
  const float* bp   = (const float*)d_in[6];
  float* out  = (float*)d_out;
  _Float16* buf0 = (_Float16*)d_ws;
  _Float16* buf1 = buf0 + (size_t)SD * HH * WW;
  _Float16* w1f  = buf1 + (size_t)SD * HH * WW;
  _Float16* w2f  = w1f + 2 * 3 * 64 * 8;

  // 64 subkeys of jax.random.split(jax.random.key(42), 64) (raw pairs, no xor)
  uint32_t ka[64], kb[64];
  for (int i = 0; i < 64; ++i) tf2x32(0u, 42u, 0u, (uint32_t)i, ka[i], kb[i]);

  hipLaunchKernelGGL(prep_kernel, dim3(1), dim3(256), 0, stream, W1, W2, w1f, w2f);
  hipLaunchKernelGGL(init_kernel, dim3((HH * WW) / 256), dim3(256), 0, stream, seed, buf0);

  dim3 grid(WW / TX, HH / TY);   // 32x32 = 1024 blocks = 4/CU exact
  _Float16* s = buf0; _Float16* d = buf1;
  for (int i = 0; i < 64; i += 2) {
    hipLaunchKernelGGL(step2_kernel, grid, dim3(512), 0, stream,
                       s, d, w1f, w2f, b1, b2, ka[i], kb[i], ka[i + 1], kb[i + 1]);
    _Float16* t = s; s = d; d = t;
  }
  hipLaunchKernelGGL(proj_kernel, dim3((HH * WW) / 256), dim3(256), 0, stream,
                     s, Wp, bp, out);
}